// Round 10
// baseline (319.217 us; speedup 1.0000x reference)
//
#include <hip/hip_runtime.h>
#include <hip/hip_fp16.h>

// LSTM: B=256, T=1024, I=64, H=25 (4H=100), O=64. fp32 in/out.
//
// R10 theory: every structure since rec6 lands at ~500-560 cy/step
//   regardless of gate source (HBM / LDS-producer / in-kernel MFMA) ->
//   the recurrence is SERIAL-CHAIN-bound (1 chain per CU; wall time =
//   1024 x chain latency). Memory is irrelevant; shorten the chain:
//   (1) 4-accumulator dots: 13-fma chain -> 7 fma + 2-add tree.
//   (2) xswap the raw rcp rB (high lanes: sB=1,dB=0 so actB==rB) -> both
//       swaps start right after their rcp; h = fma(2*Og, r2, -Og) drops
//       one chain link (2*Og, -Og computed off-chain).
//   (3) chunk 8->16: MFMA A-fragment has 16 rows (8 were junk) -> wave2
//       produces 2x steps per MFMA set; barriers 129->65; per-chunk LDS
//       read latency amortized over 16 steps.
// Structure (validated R9): ONE kernel, 3 waves/block, 1 block/batch:
//   wave0 = recurrence (lanes<32: gates i,g of unit r; lanes>=32: f,o),
//   wave1 = FC + out stores (hbuf h-ring, 32 slots),
//   wave2 = gate producer (x -> bf16 -> MFMA vs resident W_ih frags -> gbuf).
// Carried: exp2 scale folding, (i,g)/(f,o) gate layout, xswap via
//   permlane32_swap returning b (validated R4), raw s_barrier + lgkmcnt
//   drain in main loop, __syncthreads for one-time handoffs.

#define Bn 256
#define Tn 1024
#define In 64
#define Hn 25
#define Gn 100
#define On 64
#define CH 16              // steps per chunk
#define NCH (Tn / CH)      // 64 chunks

#define SCL_S -1.44269504089f   // -log2(e)   : sigmoid gates (i,f,o)
#define SCL_T -2.88539008178f   // -2*log2(e) : tanh gate (g)

typedef __attribute__((ext_vector_type(8))) short short8;
typedef __attribute__((ext_vector_type(4))) float f32x4;
typedef __attribute__((ext_vector_type(4))) int i32x4;

__device__ __forceinline__ float frcp(float x) { return __builtin_amdgcn_rcpf(x); }
__device__ __forceinline__ float ex2(float x) {
    float r;
    asm("v_exp_f32 %0, %1\n\ts_nop 1" : "=v"(r) : "v"(x));
    return r;
}
__device__ __forceinline__ float bcast(float v, int lane) {
    return __int_as_float(__builtin_amdgcn_readlane(__float_as_int(v), lane));
}
__device__ __forceinline__ float xswap(float x) {
    // returned b's LOW lanes hold the high-half value (validated R4..R9).
    float a = x, b = x;
    asm("s_nop 0\n\tv_permlane32_swap_b32 %0, %1\n\ts_nop 0"
        : "+v"(a), "+v"(b));
    return b;
}
__device__ __forceinline__ unsigned short f2bf(float f) {   // RNE fp32->bf16
    unsigned u = __float_as_uint(f);
    return (unsigned short)((u + 0x7FFFu + ((u >> 16) & 1u)) >> 16);
}
__device__ __forceinline__ int pk2(float lo, float hi) {
    return (int)(((unsigned)f2bf(hi) << 16) | f2bf(lo));
}

// gate column map: n<50: unit n>>1, gate i (even) / g (odd);
//                  n>=50: m=n-50, unit m>>1, gate f (even) / o (odd).
__device__ __forceinline__ void colmap(int n, int& g, float& scl) {
    if (n < 50) {
        const int r = n >> 1;
        g = ((n & 1) ? 2 : 0) * Hn + r;
        scl = (n & 1) ? SCL_T : SCL_S;
    } else {
        const int m = n - 50, r = m >> 1;
        g = ((m & 1) ? 3 : 1) * Hn + r;
        scl = SCL_S;
    }
}

// =====================  the single fused kernel  =========================
__global__ __launch_bounds__(192, 1)
void lstm_fused(const float* __restrict__ x, const float* __restrict__ W_ih,
                const float* __restrict__ W_hh, const float* __restrict__ b_ih,
                const float* __restrict__ b_hh, const float* __restrict__ W_fc,
                const float* __restrict__ b_fc, float* __restrict__ out) {
    __shared__ short lB[112 * 72];       // W_ih permuted+scaled bf16
    __shared__ float lbias[112];         // (b_ih+b_hh) permuted+scaled
    __shared__ short xlds[16 * 72];      // x chunk bf16, MFMA A layout
    __shared__ float gbuf[2][CH * 100];  // gates for 16 steps, dbuf
    __shared__ float hbuf[32][64];       // h ring (2 chunks deep)

    const int tid  = threadIdx.x;
    const int wid  = tid >> 6;
    const int lane = tid & 63;
    const int b    = blockIdx.x;

    // ---- cooperative staging: W_ih -> lB (bf16, colmap+scale), bias ----
    for (int i = tid; i < 112 * 64; i += 192) {
        const int n = i >> 6, k = i & 63;
        float v = 0.f;
        if (n < Gn) {
            int g; float scl;
            colmap(n, g, scl);
            v = W_ih[(size_t)g * In + k] * scl;
        }
        lB[n * 72 + k] = (short)f2bf(v);
    }
    if (tid < 112) {
        float v = 0.f;
        if (tid < Gn) {
            int g; float scl;
            colmap(tid, g, scl);
            v = (b_ih[g] + b_hh[g]) * scl;
        }
        lbias[tid] = v;
    }
    __syncthreads();

    // ---- per-wave state ----
    float wAv[25], wBv[25];          // wave0
    float c = 0.f, h = 0.f;
    float sB = 1.f, dB = 0.f;
    int coff = 0;
    float wFC[25];                   // wave1
    float bfc = 0.f;
    float* op = nullptr;
    short8 bf0[7], bf1[7];           // wave2: resident B fragments
    float biasv[7];
    float4 xr0, xr1, xr2, xr3;       // wave2: x prefetch regs (next chunk)
    const float* xb = x + (size_t)b * Tn * In;

    const int quad = lane >> 4;
    const int l16  = lane & 15;

    if (wid == 0) {
        const bool lo = lane < 32;
        const int rr  = min(lane & 31, Hn - 1);
        const float sclA = SCL_S;
        const float sclB = lo ? SCL_T : SCL_S;
        sB = lo ? 2.f : 1.f;
        dB = lo ? -1.f : 0.f;
        const float* rowA = W_hh + (size_t)((lo ? 0 : 1) * Hn + rr) * Hn;
        const float* rowB = W_hh + (size_t)((lo ? 2 : 3) * Hn + rr) * Hn;
#pragma unroll
        for (int j = 0; j < 25; ++j) {
            wAv[j] = rowA[j] * sclA;
            wBv[j] = rowB[j] * sclB;
        }
        coff = 2 * rr + (lo ? 0 : 50);
    } else if (wid == 1) {
#pragma unroll
        for (int j = 0; j < 25; ++j) wFC[j] = W_fc[(size_t)lane * Hn + j];
        bfc = b_fc[lane];
        op = out + (size_t)b * Tn * On + lane;
    } else {
        // resident B fragments + bias
#pragma unroll
        for (int nt = 0; nt < 7; ++nt) {
            const int col = nt * 16 + l16;
            bf0[nt] = *(const short8*)&lB[col * 72 + 0  + quad * 8];
            bf1[nt] = *(const short8*)&lB[col * 72 + 32 + quad * 8];
            biasv[nt] = lbias[col];
        }
        // load x chunk 0 (1024 floats; 16/lane) -> bf16 -> xlds
        const int row = lane >> 2, cb = (lane & 3) * 16;
        const float4 a = *(const float4*)(xb + lane * 16 + 0);
        const float4 d = *(const float4*)(xb + lane * 16 + 4);
        const float4 e = *(const float4*)(xb + lane * 16 + 8);
        const float4 f = *(const float4*)(xb + lane * 16 + 12);
        i32x4 p0, p1;
        p0.x = pk2(a.x, a.y); p0.y = pk2(a.z, a.w);
        p0.z = pk2(d.x, d.y); p0.w = pk2(d.z, d.w);
        p1.x = pk2(e.x, e.y); p1.y = pk2(e.z, e.w);
        p1.z = pk2(f.x, f.y); p1.w = pk2(f.z, f.w);
        *(i32x4*)&xlds[row * 72 + cb + 0] = p0;
        *(i32x4*)&xlds[row * 72 + cb + 8] = p1;
    }
    __syncthreads();   // full-drain one-time handoff

    if (wid == 2) {
        // produce chunk 0 into gbuf[0] (all 16 A-rows valid)
        const short8 a0 = *(const short8*)&xlds[l16 * 72 + 0  + quad * 8];
        const short8 a1 = *(const short8*)&xlds[l16 * 72 + 32 + quad * 8];
#pragma unroll
        for (int nt = 0; nt < 7; ++nt) {
            f32x4 acc = {biasv[nt], biasv[nt], biasv[nt], biasv[nt]};
            acc = __builtin_amdgcn_mfma_f32_16x16x32_bf16(a0, bf0[nt], acc, 0, 0, 0);
            acc = __builtin_amdgcn_mfma_f32_16x16x32_bf16(a1, bf1[nt], acc, 0, 0, 0);
            const int col = nt * 16 + l16;
            if (col < Gn) {
#pragma unroll
                for (int i = 0; i < 4; ++i)
                    gbuf[0][(quad * 4 + i) * 100 + col] = acc[i];
            }
        }
        // prefetch x for chunk 1
        const float* xs = xb + 1024;
        xr0 = *(const float4*)(xs + lane * 16 + 0);
        xr1 = *(const float4*)(xs + lane * 16 + 4);
        xr2 = *(const float4*)(xs + lane * 16 + 8);
        xr3 = *(const float4*)(xs + lane * 16 + 12);
    }
    __syncthreads();   // chunk 0 visible to wave0

    // =========================== main loop ==============================
#pragma unroll 1
    for (int k = 0; k <= NCH; ++k) {
        if (wid == 0) {
            if (k < NCH) {
                const int kb = k & 1;
                float2 g[CH];
#pragma unroll
                for (int s = 0; s < CH; ++s)
                    g[s] = *(const float2*)&gbuf[kb][s * 100 + coff];
#pragma unroll
                for (int s = 0; s < CH; ++s) {
                    // 4-accumulator dot (chain: 7 fma + 2 adds)
                    float aA0 = g[s].x, aA1 = 0.f, aA2 = 0.f, aA3 = 0.f;
                    float aB0 = g[s].y, aB1 = 0.f, aB2 = 0.f, aB3 = 0.f;
#pragma unroll
                    for (int j = 0; j < 24; j += 4) {
                        const float h0 = bcast(h, j);
                        const float h1 = bcast(h, j + 1);
                        const float h2 = bcast(h, j + 2);
                        const float h3 = bcast(h, j + 3);
                        aA0 = fmaf(wAv[j],     h0, aA0);
                        aB0 = fmaf(wBv[j],     h0, aB0);
                        aA1 = fmaf(wAv[j + 1], h1, aA1);
                        aB1 = fmaf(wBv[j + 1], h1, aB1);
                        aA2 = fmaf(wAv[j + 2], h2, aA2);
                        aB2 = fmaf(wBv[j + 2], h2, aB2);
                        aA3 = fmaf(wAv[j + 3], h3, aA3);
                        aB3 = fmaf(wBv[j + 3], h3, aB3);
                    }
                    {
                        const float h0 = bcast(h, 24);
                        aA0 = fmaf(wAv[24], h0, aA0);
                        aB0 = fmaf(wBv[24], h0, aB0);
                    }
                    const float aA = (aA0 + aA1) + (aA2 + aA3);
                    const float aB = (aB0 + aB1) + (aB2 + aB3);

                    const float rA = frcp(1.f + ex2(aA));   // low: I ; high: F
                    const float rB = frcp(1.f + ex2(aB));   // low: sg(2g'); high: O
                    const float Fg = xswap(rA);             // low lanes: F
                    const float Og = xswap(rB);             // low lanes: O
                    const float actB = fmaf(sB, rB, dB);    // low: G = 2rB-1
                    c = fmaf(Fg, c, rA * actB);             // valid lanes 0..24
                    const float r2 = frcp(1.f + ex2(c * SCL_T));
                    h = fmaf(Og + Og, r2, -Og);             // h = O*(2r2-1)

                    hbuf[(k * CH + s) & 31][lane] = h;      // junk lanes 25+
                }
            }
        } else if (wid == 1) {
            if (k >= 1) {
#pragma unroll
                for (int s = 0; s < CH; ++s) {
                    const int t = (k - 1) * CH + s;
                    const int sl = t & 31;
                    float a0 = bfc, a1 = 0.f;
#pragma unroll
                    for (int j = 0; j < 24; j += 2) {
                        a0 = fmaf(hbuf[sl][j],     wFC[j],     a0);
                        a1 = fmaf(hbuf[sl][j + 1], wFC[j + 1], a1);
                    }
                    a0 = fmaf(hbuf[sl][24], wFC[24], a0);
                    op[(size_t)t * On] = a0 + a1;
                }
            }
        } else {
            if (k < NCH - 1) {
                // produce chunk k+1 from prefetched regs (vmcnt auto-wait)
                const int row = lane >> 2, cb = (lane & 3) * 16;
                i32x4 p0, p1;
                p0.x = pk2(xr0.x, xr0.y); p0.y = pk2(xr0.z, xr0.w);
                p0.z = pk2(xr1.x, xr1.y); p0.w = pk2(xr1.z, xr1.w);
                p1.x = pk2(xr2.x, xr2.y); p1.y = pk2(xr2.z, xr2.w);
                p1.z = pk2(xr3.x, xr3.y); p1.w = pk2(xr3.z, xr3.w);
                *(i32x4*)&xlds[row * 72 + cb + 0] = p0;
                *(i32x4*)&xlds[row * 72 + cb + 8] = p1;
                // prefetch x for chunk k+2
                if (k < NCH - 2) {
                    const float* xs = xb + (size_t)(k + 2) * (CH * In);
                    xr0 = *(const float4*)(xs + lane * 16 + 0);
                    xr1 = *(const float4*)(xs + lane * 16 + 4);
                    xr2 = *(const float4*)(xs + lane * 16 + 8);
                    xr3 = *(const float4*)(xs + lane * 16 + 12);
                }
                asm volatile("s_waitcnt lgkmcnt(0)" ::: "memory");
                const short8 a0 = *(const short8*)&xlds[l16 * 72 + 0  + quad * 8];
                const short8 a1 = *(const short8*)&xlds[l16 * 72 + 32 + quad * 8];
                const int nb = (k + 1) & 1;
#pragma unroll
                for (int nt = 0; nt < 7; ++nt) {
                    f32x4 acc = {biasv[nt], biasv[nt], biasv[nt], biasv[nt]};
                    acc = __builtin_amdgcn_mfma_f32_16x16x32_bf16(a0, bf0[nt], acc, 0, 0, 0);
                    acc = __builtin_amdgcn_mfma_f32_16x16x32_bf16(a1, bf1[nt], acc, 0, 0, 0);
                    const int col = nt * 16 + l16;
                    if (col < Gn) {
#pragma unroll
                        for (int i = 0; i < 4; ++i)
                            gbuf[nb][(quad * 4 + i) * 100 + col] = acc[i];
                    }
                }
            }
        }
        // raw barrier (R6..R9-proven): drain LDS only; x prefetch in flight
        asm volatile("s_waitcnt lgkmcnt(0)" ::: "memory");
        __builtin_amdgcn_s_barrier();
        asm volatile("" ::: "memory");
    }
}

extern "C" void kernel_launch(void* const* d_in, const int* in_sizes, int n_in,
                              void* d_out, int out_size, void* d_ws, size_t ws_size,
                              hipStream_t stream) {
    const float* x    = (const float*)d_in[0];
    const float* W_ih = (const float*)d_in[1];
    const float* W_hh = (const float*)d_in[2];
    const float* b_ih = (const float*)d_in[3];
    const float* b_hh = (const float*)d_in[4];
    const float* W_fc = (const float*)d_in[5];
    const float* b_fc = (const float*)d_in[6];
    float* out = (float*)d_out;

    lstm_fused<<<Bn, 192, 0, stream>>>(x, W_ih, W_hh, b_ih, b_hh,
                                       W_fc, b_fc, out);
}